// Round 1
// baseline (76.821 us; speedup 1.0000x reference)
//
#include <hip/hip_runtime.h>
#include <math.h>

// Problem constants (fixed by setup_inputs: N=8, C=3, ph=pw=256, S=1024)
#define S   1024
#define PH  256
#define NP  8

// One thread per output pixel (h,w), handles all 3 channels.
// Exact-FP replication of the reference:
//   xn = (w+0.5)*2/S - 1 ; gx = xn - tx ; px = ((gx+1)*S - 1)*0.5
//   bilinear taps at floor(px)/floor(px)+1 with weights (1-f, f)
//   mask = (sum of valid-tap weights == 1.0f) ? 1 : 0   [mask canvas is all-ones]
//   patch value = 4-tap weighted sum of padded patch, * mask
//   composite: nonzero overwrites, patches applied i=0..7 in order.
// All interp arithmetic uses __f*_rn intrinsics so the compiler cannot
// FMA-contract and diverge from the numpy reference's per-op rounding.
__global__ __launch_bounds__(256)
void PatchTransformer_kernel(const float* __restrict__ adv,   // [8,3,256,256]
                             const float* __restrict__ loc,   // [8,2]
                             const float* __restrict__ img,   // [3,1024,1024]
                             float* __restrict__ out)         // [3,1024,1024]
{
    int idx = blockIdx.x * blockDim.x + threadIdx.x;
    if (idx >= S * S) return;
    const int w = idx & (S - 1);
    const int h = idx >> 10;

    // normalized grid coords, exact op order of reference
    const float xn = __fsub_rn(__fdiv_rn(__fmul_rn(__fadd_rn((float)w, 0.5f), 2.0f), (float)S), 1.0f);
    const float yn = __fsub_rn(__fdiv_rn(__fmul_rn(__fadd_rn((float)h, 0.5f), 2.0f), (float)S), 1.0f);

    float v0 = img[idx];
    float v1 = img[idx + S * S];
    float v2 = img[idx + 2 * S * S];

    #pragma unroll
    for (int i = 0; i < NP; ++i) {
        const float tx = loc[2 * i + 0];
        const float ty = loc[2 * i + 1];
        const float gx = __fsub_rn(xn, tx);
        const float gy = __fsub_rn(yn, ty);
        const float px = __fmul_rn(__fsub_rn(__fmul_rn(__fadd_rn(gx, 1.0f), (float)S), 1.0f), 0.5f);
        const float py = __fmul_rn(__fsub_rn(__fmul_rn(__fadd_rn(gy, 1.0f), (float)S), 1.0f), 0.5f);

        // Outside (-1, 256)^2 every patch tap is exactly 0 -> transparent -> skip.
        if (px <= -1.0f || px >= (float)PH || py <= -1.0f || py >= (float)PH) continue;

        const float x0f = floorf(px), y0f = floorf(py);
        const float wx1 = __fsub_rn(px, x0f);
        const float wy1 = __fsub_rn(py, y0f);
        const float wx0 = __fsub_rn(1.0f, wx1);
        const float wy0 = __fsub_rn(1.0f, wy1);
        const float p00 = __fmul_rn(wy0, wx0);
        const float p01 = __fmul_rn(wy0, wx1);
        const float p10 = __fmul_rn(wy1, wx0);
        const float p11 = __fmul_rn(wy1, wx1);

        const int ix0 = (int)x0f, iy0 = (int)y0f;   // in [-1, 255]
        const int ix1 = ix0 + 1,  iy1 = iy0 + 1;    // in [0, 256]

        // canvas validity (upper bound S never hit inside pruned region)
        const float m00 = (iy0 >= 0 && ix0 >= 0) ? 1.0f : 0.0f;
        const float m01 = (iy0 >= 0)             ? 1.0f : 0.0f;
        const float m10 = (ix0 >= 0)             ? 1.0f : 0.0f;
        const float m11 = 1.0f;
        const float mval =
            __fadd_rn(__fadd_rn(__fadd_rn(__fmul_rn(m00, p00),
                                          __fmul_rn(m01, p01)),
                                __fmul_rn(m10, p10)),
                      __fmul_rn(m11, p11));
        // mask != 1 -> patch_w = val*0 = +-0 -> transparent -> skip (exact)
        if (mval != 1.0f) continue;

        // padded-canvas tap is nonzero only inside [0,256)^2
        const bool bx0 = (ix0 >= 0) && (ix0 < PH);
        const bool bx1 = (ix1 < PH);
        const bool by0 = (iy0 >= 0) && (iy0 < PH);
        const bool by1 = (iy1 < PH);
        const int o00 = iy0 * PH + ix0;
        const int o01 = iy0 * PH + ix1;
        const int o10 = iy1 * PH + ix0;
        const int o11 = iy1 * PH + ix1;
        const float* advi = adv + (size_t)i * 3 * PH * PH;

        #pragma unroll
        for (int c = 0; c < 3; ++c) {
            const float* a = advi + c * PH * PH;
            const float g00 = (by0 && bx0) ? a[o00] : 0.0f;
            const float g01 = (by0 && bx1) ? a[o01] : 0.0f;
            const float g10 = (by1 && bx0) ? a[o10] : 0.0f;
            const float g11 = (by1 && bx1) ? a[o11] : 0.0f;
            const float val =
                __fadd_rn(__fadd_rn(__fadd_rn(__fmul_rn(g00, p00),
                                              __fmul_rn(g01, p01)),
                                    __fmul_rn(g10, p10)),
                          __fmul_rn(g11, p11));
            if (val != 0.0f) {
                if (c == 0) v0 = val;
                else if (c == 1) v1 = val;
                else v2 = val;
            }
        }
    }

    out[idx]             = v0;
    out[idx + S * S]     = v1;
    out[idx + 2 * S * S] = v2;
}

extern "C" void kernel_launch(void* const* d_in, const int* in_sizes, int n_in,
                              void* d_out, int out_size, void* d_ws, size_t ws_size,
                              hipStream_t stream) {
    const float* adv = (const float*)d_in[0];   // (8,3,256,256) f32
    const float* loc = (const float*)d_in[1];   // (8,2) f32
    const float* img = (const float*)d_in[2];   // (3,1024,1024) f32
    float* out = (float*)d_out;                 // (1,3,1024,1024) f32

    dim3 block(256);
    dim3 grid((S * S + 255) / 256);
    hipLaunchKernelGGL(PatchTransformer_kernel, grid, block, 0, stream,
                       adv, loc, img, out);
}